// Round 7
// baseline (2497.019 us; speedup 1.0000x reference)
//
#include <hip/hip_runtime.h>
#include <math.h>

// Problem constants (fixed by setup_inputs)
#define NROWS 8192
#define DIN   2048
#define HF    512
#define NAUG  513      // H+1
#define OOUT  32
#define SRLS  2048     // ceil(0.25 * 8192), epoch = 2
#define LDP   576      // Phi row stride
#define NPAD  576      // padded Cholesky dimension (9 x 64)

typedef short bf16x8 __attribute__((ext_vector_type(8)));
typedef float f32x4  __attribute__((ext_vector_type(4)));

// ---------------------------------------------------------------------------
// Kernel 0: split fp32 -> (hi, lo) bf16 pair via truncation.
// ---------------------------------------------------------------------------
__global__ __launch_bounds__(256) void split32(const float* __restrict__ s,
                                               unsigned short* __restrict__ hi,
                                               unsigned short* __restrict__ lo,
                                               int n4)
{
    int stride = gridDim.x * blockDim.x;
    for (int i = blockIdx.x * blockDim.x + threadIdx.x; i < n4; i += stride) {
        float4 v = ((const float4*)s)[i];
        float vv[4] = {v.x, v.y, v.z, v.w};
        ushort4 h, l;
        unsigned short hh[4], ll[4];
#pragma unroll
        for (int j = 0; j < 4; ++j) {
            unsigned int bits = __float_as_uint(vv[j]);
            float hf = __uint_as_float(bits & 0xFFFF0000u);
            float rf = vv[j] - hf;
            hh[j] = (unsigned short)(bits >> 16);
            ll[j] = (unsigned short)(__float_as_uint(rf) >> 16);
        }
        h.x = hh[0]; h.y = hh[1]; h.z = hh[2]; h.w = hh[3];
        l.x = ll[0]; l.y = ll[1]; l.z = ll[2]; l.w = ll[3];
        ((ushort4*)hi)[i] = h;
        ((ushort4*)lo)[i] = l;
    }
}

__device__ __forceinline__ void gl_lds16(const unsigned short* g, unsigned short* l)
{
    __builtin_amdgcn_global_load_lds(
        (const __attribute__((address_space(1))) unsigned int*)g,
        (__attribute__((address_space(3))) unsigned int*)l, 16, 0, 0);
}

// ---------------------------------------------------------------------------
// Kernel 1: Phi[:, :512] = relu(x @ W1^T + b1) via 3-term split-bf16 MFMA.
// ---------------------------------------------------------------------------
__global__ __launch_bounds__(256) void phi_mfma(const unsigned short* __restrict__ Ahi,
                                                const unsigned short* __restrict__ Alo,
                                                const unsigned short* __restrict__ Bhi,
                                                const unsigned short* __restrict__ Blo,
                                                const float* __restrict__ b1,
                                                float* __restrict__ Phi)
{
    __shared__ unsigned short sAhi[128 * 32], sAlo[128 * 32];
    __shared__ unsigned short sBhi[64 * 32],  sBlo[64 * 32];
    const int tid = threadIdx.x;
    const int bx = blockIdx.x & 7;
    const int by = blockIdx.x >> 3;
    const int row0 = by * 128, col0 = bx * 64;
    const int wave = tid >> 6, lane = tid & 63;
    const int wr = wave >> 1, wc = wave & 1;
    const int sr = tid >> 2, sk = (tid & 3) * 8;

    f32x4 acc[4][2] = {};

    for (int k0 = 0; k0 < DIN; k0 += 32) {
        gl_lds16(&Ahi[(size_t)(row0 + sr) * DIN + k0 + sk],      &sAhi[sr * 32 + sk]);
        gl_lds16(&Ahi[(size_t)(row0 + 64 + sr) * DIN + k0 + sk], &sAhi[(64 + sr) * 32 + sk]);
        gl_lds16(&Alo[(size_t)(row0 + sr) * DIN + k0 + sk],      &sAlo[sr * 32 + sk]);
        gl_lds16(&Alo[(size_t)(row0 + 64 + sr) * DIN + k0 + sk], &sAlo[(64 + sr) * 32 + sk]);
        gl_lds16(&Bhi[(size_t)(col0 + sr) * DIN + k0 + sk],      &sBhi[sr * 32 + sk]);
        gl_lds16(&Blo[(size_t)(col0 + sr) * DIN + k0 + sk],      &sBlo[sr * 32 + sk]);
        __syncthreads();

        const int rA = lane & 15;
        const int ko = (lane >> 4) * 8;
        bf16x8 ah[4], al[4], bh[2], bl[2];
#pragma unroll
        for (int m = 0; m < 4; ++m) {
            int r = wr * 64 + m * 16 + rA;
            ah[m] = *(const bf16x8*)&sAhi[r * 32 + ko];
            al[m] = *(const bf16x8*)&sAlo[r * 32 + ko];
        }
#pragma unroll
        for (int n = 0; n < 2; ++n) {
            int cC = wc * 32 + n * 16 + rA;
            bh[n] = *(const bf16x8*)&sBhi[cC * 32 + ko];
            bl[n] = *(const bf16x8*)&sBlo[cC * 32 + ko];
        }
#pragma unroll
        for (int m = 0; m < 4; ++m)
#pragma unroll
            for (int n = 0; n < 2; ++n) {
                acc[m][n] = __builtin_amdgcn_mfma_f32_16x16x32_bf16(ah[m], bh[n], acc[m][n], 0, 0, 0);
                acc[m][n] = __builtin_amdgcn_mfma_f32_16x16x32_bf16(ah[m], bl[n], acc[m][n], 0, 0, 0);
                acc[m][n] = __builtin_amdgcn_mfma_f32_16x16x32_bf16(al[m], bh[n], acc[m][n], 0, 0, 0);
            }
        __syncthreads();
    }

#pragma unroll
    for (int n = 0; n < 2; ++n) {
        int col = col0 + wc * 32 + n * 16 + (lane & 15);
        float bb = b1[col];
#pragma unroll
        for (int m = 0; m < 4; ++m) {
            int rbase = row0 + wr * 64 + m * 16 + (lane >> 4) * 4;
#pragma unroll
            for (int r = 0; r < 4; ++r) {
                float v = acc[m][n][r] + bb;
                Phi[(size_t)(rbase + r) * LDP + col] = fmaxf(v, 0.0f);
            }
        }
    }
}

// ---------------------------------------------------------------------------
// Kernel 2: ones column only (y is read directly by gram_part now)
// ---------------------------------------------------------------------------
__global__ void aux_fill(float* __restrict__ Phi)
{
    int r = blockIdx.x * blockDim.x + threadIdx.x;
    if (r < NROWS) Phi[(size_t)r * LDP + 512] = 1.0f;
}

// Gd := I (fp64 576x576)
__global__ void gd_init(double* __restrict__ Gd)
{
    int idx = blockIdx.x * blockDim.x + threadIdx.x;
    int i = idx / NPAD, j = idx - i * NPAD;
    Gd[idx] = (i == j) ? 1.0 : 0.0;
}

// ---------------------------------------------------------------------------
// Kernel 3a: gram partial tiles. 170 pairs x 8 row-chunks of 256.
// pr<153: lower tile (bi>=bj) of Phi^T Phi. pr>=153: Phi^T y tile.
// ---------------------------------------------------------------------------
__global__ __launch_bounds__(256) void gram_part(const float* __restrict__ Phi,
                                                 const float* __restrict__ y,
                                                 double* __restrict__ Gp)
{
    const int pr = blockIdx.x % 170;
    const int ch = blockIdx.x / 170;
    __shared__ float Ta[32][33];
    __shared__ float Tb[32][33];
    const int tid = threadIdx.x;
    const int tx = tid & 15, ty = tid >> 4;
    int i0, j0; bool ytile;
    if (pr < 153) {
        int rem = pr, bj = 0;
        while (rem >= 17 - bj) { rem -= 17 - bj; ++bj; }
        int bi = bj + rem;
        i0 = bi * 32; j0 = bj * 32; ytile = false;
    } else {
        i0 = (pr - 153) * 32; j0 = 0; ytile = true;
    }
    double acc00 = 0., acc01 = 0., acc10 = 0., acc11 = 0.;
    const int sBase = ch * 256;
    for (int s0 = sBase; s0 < sBase + 256; s0 += 32) {
        int r = tid >> 3, c4 = (tid & 7) * 4;
        float4 va = *(const float4*)&Phi[(size_t)(s0 + r) * LDP + i0 + c4];
        Ta[r][c4 + 0] = va.x; Ta[r][c4 + 1] = va.y;
        Ta[r][c4 + 2] = va.z; Ta[r][c4 + 3] = va.w;
        float4 vb = ytile ? *(const float4*)&y[(size_t)(s0 + r) * 32 + c4]
                          : *(const float4*)&Phi[(size_t)(s0 + r) * LDP + j0 + c4];
        Tb[r][c4 + 0] = vb.x; Tb[r][c4 + 1] = vb.y;
        Tb[r][c4 + 2] = vb.z; Tb[r][c4 + 3] = vb.w;
        __syncthreads();
#pragma unroll
        for (int s = 0; s < 32; ++s) {
            double a0 = (double)Ta[s][ty * 2], a1 = (double)Ta[s][ty * 2 + 1];
            double b0 = (double)Tb[s][tx * 2], b1v = (double)Tb[s][tx * 2 + 1];
            acc00 += a0 * b0; acc01 += a0 * b1v;
            acc10 += a1 * b0; acc11 += a1 * b1v;
        }
        __syncthreads();
    }
    size_t base = ((size_t)pr * 8 + ch) * 1024;
    double accs[2][2] = {{acc00, acc01}, {acc10, acc11}};
#pragma unroll
    for (int ii = 0; ii < 2; ++ii)
#pragma unroll
        for (int jj = 0; jj < 2; ++jj)
            Gp[base + (size_t)(ty * 2 + ii) * 32 + tx * 2 + jj] = accs[ii][jj];
}

// Kernel 3b: sum 8 chunks, write Gd (both triangles, +I on diag) / By
__global__ __launch_bounds__(256) void gram_reduce(const double* __restrict__ Gp,
                                                   double* __restrict__ Gd,
                                                   double* __restrict__ By)
{
    const int pr = blockIdx.x;
    const int tid = threadIdx.x;
    for (int e = tid; e < 1024; e += 256) {
        double s = 0.0;
#pragma unroll
        for (int ch = 0; ch < 8; ++ch)
            s += Gp[((size_t)pr * 8 + ch) * 1024 + e];
        int er = e >> 5, ec = e & 31;
        if (pr < 153) {
            int rem = pr, bj = 0;
            while (rem >= 17 - bj) { rem -= 17 - bj; ++bj; }
            int bi = bj + rem;
            int gi = bi * 32 + er, gj = bj * 32 + ec;
            if (gi < NAUG && gj < NAUG) {
                double v = s + ((gi == gj) ? 1.0 : 0.0);
                Gd[(size_t)gi * NPAD + gj] = v;
                if (bi != bj) Gd[(size_t)gj * NPAD + gi] = v;
            }
        } else {
            int gi = (pr - 153) * 32 + er;
            if (gi < NAUG) By[gi * 32 + ec] = s;
        }
    }
}

// ---------------------------------------------------------------------------
// Kernel 5: 64x64 fp64 Cholesky + inverse, register-panel version.
// Phase 1 per 8-col panel: (a) 8 lanes factor the 8x8 diag block in REGISTERS
// (shfl broadcasts), (b) tall rows forward-solved fully parallel in registers,
// (c) rank-8 trailing update. Phase 2: inverse with register triangle solves.
// ---------------------------------------------------------------------------
__global__ __launch_bounds__(256) void chol_diag(double* __restrict__ Gd,
                                                 double* __restrict__ Dinv, int p)
{
    __shared__ double A[64][65];
    __shared__ double Zs[64][65];
    __shared__ double L8[8][9];
    const int tid = threadIdx.x;
    const int r0g = p * 64;
    for (int idx = tid; idx < 4096; idx += 256) {
        int r = idx >> 6, c = idx & 63;
        A[r][c] = Gd[(size_t)(r0g + r) * NPAD + r0g + c];
    }
    __syncthreads();

    // ---- Phase 1 ----
    for (int kb = 0; kb < 8; ++kb) {
        const int k0 = kb * 8;
        // (a) 8x8 register factor, lanes 0..7 (lane = row)
        if (tid < 8) {
            const int r = tid;
            double a[8];
#pragma unroll
            for (int c = 0; c < 8; ++c) a[c] = A[k0 + r][k0 + c];
#pragma unroll
            for (int k = 0; k < 8; ++k) {
                double dk = __shfl(a[k], k, 64);
                double s  = sqrt(dk);
                double inv = 1.0 / s;
                if (r == k) a[k] = s;
                else if (r > k) a[k] *= inv;
                double lrk = a[k];
#pragma unroll
                for (int j = k + 1; j < 8; ++j) {
                    double ljk = __shfl(a[k], j, 64);
                    if (r >= j) a[j] -= lrk * ljk;
                }
            }
#pragma unroll
            for (int c = 0; c < 8; ++c) {
                L8[r][c] = (c <= r) ? a[c] : 0.0;
                A[k0 + r][k0 + c] = a[c];
            }
        }
        __syncthreads();
        // (b) tall rows: forward solve L8 * l = a_i in registers (parallel)
        const int iRow = k0 + 8 + (tid >> 2);
        const int cg = tid & 3;
        double l[8];
        if (iRow < 64) {
#pragma unroll
            for (int k = 0; k < 8; ++k) l[k] = A[iRow][k0 + k];
#pragma unroll
            for (int k = 0; k < 8; ++k) {
                l[k] /= L8[k][k];
#pragma unroll
                for (int j = k + 1; j < 8; ++j) l[j] -= l[k] * L8[j][k];
            }
            if (cg == 0) {
#pragma unroll
                for (int k = 0; k < 8; ++k) A[iRow][k0 + k] = l[k];
            }
        }
        __syncthreads();
        // (c) rank-8 trailing update (lower)
        if (iRow < 64) {
            for (int j = k0 + 8 + cg; j <= iRow; j += 4) {
                double s = A[iRow][j];
#pragma unroll
                for (int k = 0; k < 8; ++k) s -= l[k] * A[j][k0 + k];
                A[iRow][j] = s;
            }
        }
        __syncthreads();
    }

    // ---- Phase 2: Zs = inv(L) ----
    for (int rb = 0; rb < 8; ++rb) {
        const int r0 = rb * 8;
        const int c = tid & 63, pg = tid >> 6;     // rows pg, pg+4 of block
        double t0 = 0.0, t1 = 0.0;
        for (int q = 0; q < r0; ++q) {
            double zqc = Zs[q][c];
            t0 += A[r0 + pg][q] * zqc;
            t1 += A[r0 + pg + 4][q] * zqc;
        }
        Zs[r0 + pg][c]     = ((r0 + pg) == c ? 1.0 : 0.0) - t0;
        Zs[r0 + pg + 4][c] = ((r0 + pg + 4) == c ? 1.0 : 0.0) - t1;
        __syncthreads();
        if (tid < 64) {                            // register triangle solve
            double z[8];
#pragma unroll
            for (int q = 0; q < 8; ++q) z[q] = Zs[r0 + q][tid];
#pragma unroll
            for (int q = 0; q < 8; ++q) {
#pragma unroll
                for (int w = 0; w < q; ++w) z[q] -= A[r0 + q][r0 + w] * z[w];
                z[q] /= A[r0 + q][r0 + q];
            }
#pragma unroll
            for (int q = 0; q < 8; ++q) Zs[r0 + q][tid] = z[q];
        }
        __syncthreads();
    }

    for (int idx = tid; idx < 4096; idx += 256) {
        int r = idx >> 6, c = idx & 63;
        Gd[(size_t)(r0g + r) * NPAD + r0g + c] = A[r][c];
        Dinv[(size_t)p * 4096 + idx] = (c <= r) ? Zs[r][c] : 0.0;
    }
}

// ---------------------------------------------------------------------------
// Kernel 6: fused TRSM + SYRK per panel. Block (i,j), p<j<=i<=8: compute
// Li = A_ip*Dinv^T, Lj likewise; Gd[i][j] -= Li*Lj^T. j==p+1 blocks write
// Li to Lmat (separate buffer -> no read/write race on Gd panels).
// ---------------------------------------------------------------------------
__global__ __launch_bounds__(256) void panel_up(double* __restrict__ Gd,
                                                const double* __restrict__ Dinv,
                                                double* __restrict__ Lmat, int p)
{
    __shared__ double Dv[64][65];
    __shared__ double Ai[64][65];
    __shared__ double Aj[64][65];
    const int m = 8 - p;
    int b = blockIdx.x, jj = 0;
    while (b >= m - jj) { b -= m - jj; ++jj; }
    const int jB = p + 1 + jj, iB = jB + b;
    const int d0 = p * 64, i0 = iB * 64, j0 = jB * 64;
    const int tid = threadIdx.x;
    const bool diag = (iB == jB);
    const double* Dp = Dinv + (size_t)p * 4096;
    for (int idx = tid; idx < 4096; idx += 256) {
        int r = idx >> 6, cc = idx & 63;
        Dv[r][cc] = Dp[idx];
        Ai[r][cc] = Gd[(size_t)(i0 + r) * NPAD + d0 + cc];
        if (!diag) Aj[r][cc] = Gd[(size_t)(j0 + r) * NPAD + d0 + cc];
    }
    __syncthreads();
    const int tx = tid & 15, ty = tid >> 4;
    double li[4][4] = {}, lj[4][4] = {};
    for (int q = 0; q < 64; ++q) {
        double dvq[4], av[4];
#pragma unroll
        for (int v = 0; v < 4; ++v) dvq[v] = Dv[tx * 4 + v][q];
#pragma unroll
        for (int u = 0; u < 4; ++u) av[u] = Ai[ty * 4 + u][q];
#pragma unroll
        for (int u = 0; u < 4; ++u)
#pragma unroll
            for (int v = 0; v < 4; ++v) li[u][v] += av[u] * dvq[v];
        if (!diag) {
#pragma unroll
            for (int u = 0; u < 4; ++u) av[u] = Aj[ty * 4 + u][q];
#pragma unroll
            for (int u = 0; u < 4; ++u)
#pragma unroll
                for (int v = 0; v < 4; ++v) lj[u][v] += av[u] * dvq[v];
        }
    }
    __syncthreads();
#pragma unroll
    for (int u = 0; u < 4; ++u)
#pragma unroll
        for (int v = 0; v < 4; ++v) {
            Ai[ty * 4 + u][tx * 4 + v] = li[u][v];
            if (!diag) Aj[ty * 4 + u][tx * 4 + v] = lj[u][v];
        }
    __syncthreads();
    if (jj == 0) {          // unique writer of Lmat[iB][p]
        double* dst = Lmat + ((size_t)iB * 9 + p) * 4096;
        for (int idx = tid; idx < 4096; idx += 256)
            dst[idx] = Ai[idx >> 6][idx & 63];
    }
    double acc[4][4] = {};
    for (int q = 0; q < 64; ++q) {
        double a_[4], b_[4];
#pragma unroll
        for (int u = 0; u < 4; ++u) a_[u] = Ai[ty * 4 + u][q];
#pragma unroll
        for (int v = 0; v < 4; ++v) b_[v] = diag ? Ai[tx * 4 + v][q] : Aj[tx * 4 + v][q];
#pragma unroll
        for (int u = 0; u < 4; ++u)
#pragma unroll
            for (int v = 0; v < 4; ++v) acc[u][v] += a_[u] * b_[v];
    }
#pragma unroll
    for (int u = 0; u < 4; ++u)
#pragma unroll
        for (int v = 0; v < 4; ++v) {
            size_t off = (size_t)(i0 + ty * 4 + u) * NPAD + j0 + tx * 4 + v;
            Gd[off] -= acc[u][v];
        }
}

// ---------------------------------------------------------------------------
// Kernel 8: M[i][j] = L[i][j]*Dinv_j ; N[i][j] = Dinv_i*L[i][j]  (L from Lmat)
// ---------------------------------------------------------------------------
__global__ __launch_bounds__(256) void mnprep(const double* __restrict__ Lmat,
                                              const double* __restrict__ Dinv,
                                              double* __restrict__ Mb,
                                              double* __restrict__ Nb)
{
    __shared__ double Ls[64][65];
    __shared__ double Ds[64][65];
    int b = blockIdx.x;
    const bool doN = (b >= 36);
    if (doN) b -= 36;
    int jj = 0, rem = b;
    while (rem >= 8 - jj) { rem -= 8 - jj; ++jj; }
    const int ii = jj + 1 + rem;
    const int tid = threadIdx.x;
    const double* Dv = Dinv + (size_t)(doN ? ii : jj) * 4096;
    const double* Lsrc = Lmat + ((size_t)ii * 9 + jj) * 4096;
    for (int idx = tid; idx < 4096; idx += 256) {
        Ls[idx >> 6][idx & 63] = Lsrc[idx];
        Ds[idx >> 6][idx & 63] = Dv[idx];
    }
    __syncthreads();
    const int tx = tid & 15, ty = tid >> 4;
    double acc[4][4] = {};
    for (int k = 0; k < 64; ++k) {
        double a[4], bb[4];
        if (!doN) {
#pragma unroll
            for (int u = 0; u < 4; ++u) a[u]  = Ls[ty * 4 + u][k];
#pragma unroll
            for (int v = 0; v < 4; ++v) bb[v] = Ds[k][tx * 4 + v];
        } else {
#pragma unroll
            for (int u = 0; u < 4; ++u) a[u]  = Ds[ty * 4 + u][k];
#pragma unroll
            for (int v = 0; v < 4; ++v) bb[v] = Ls[k][tx * 4 + v];
        }
#pragma unroll
        for (int u = 0; u < 4; ++u)
#pragma unroll
            for (int v = 0; v < 4; ++v) acc[u][v] += a[u] * bb[v];
    }
    double* dst = (doN ? Nb : Mb) + (size_t)(ii * 9 + jj) * 4096;
#pragma unroll
    for (int u = 0; u < 4; ++u)
#pragma unroll
        for (int v = 0; v < 4; ++v)
            dst[(ty * 4 + u) * 64 + tx * 4 + v] = acc[u][v];
}

// ---------------------------------------------------------------------------
// Kernel 9: full block-triangular solve chain in ONE workgroup.
// B (576x32 fp64) LDS-resident; M/N/Dinv streamed from L2. ~20 barriers.
// ---------------------------------------------------------------------------
__global__ __launch_bounds__(1024) void sweep_all(const double* __restrict__ Mb,
                                                  const double* __restrict__ Nb,
                                                  const double* __restrict__ Dinv,
                                                  const double* __restrict__ By,
                                                  const float* __restrict__ W0,
                                                  float* __restrict__ Xs)
{
    __shared__ double Bl[NPAD][32];
    const int tid = threadIdx.x;
    const int c = tid & 31, rg = tid >> 5;     // rg 0..31

    for (int i = rg; i < NPAD; i += 32)
        Bl[i][c] = (i < NAUG) ? (double)W0[i * 32 + c] + By[i * 32 + c] : 0.0;
    __syncthreads();

    // forward: B[i] -= M[i][j] * B[j]
    for (int j = 0; j < 8; ++j) {
        for (int bi2 = j + 1; bi2 <= 8; ++bi2) {
            const double* Mblk = Mb + ((size_t)bi2 * 9 + j) * 4096;
            double a0 = 0.0, a1 = 0.0;
            for (int k = 0; k < 64; ++k) {
                double bk = Bl[j * 64 + k][c];
                a0 += Mblk[rg * 64 + k] * bk;
                a1 += Mblk[(rg + 32) * 64 + k] * bk;
            }
            Bl[bi2 * 64 + rg][c]      -= a0;
            Bl[bi2 * 64 + rg + 32][c] -= a1;
        }
        __syncthreads();
    }
    // ydiag: B[i] = Dinv_i * B[i]
    {
        double r0v[9], r1v[9];
#pragma unroll
        for (int i2 = 0; i2 < 9; ++i2) {
            const double* Dv = Dinv + (size_t)i2 * 4096;
            double a0 = 0.0, a1 = 0.0;
            for (int k = 0; k < 64; ++k) {
                double bk = Bl[i2 * 64 + k][c];
                a0 += Dv[rg * 64 + k] * bk;
                a1 += Dv[(rg + 32) * 64 + k] * bk;
            }
            r0v[i2] = a0; r1v[i2] = a1;
        }
        __syncthreads();
#pragma unroll
        for (int i2 = 0; i2 < 9; ++i2) {
            Bl[i2 * 64 + rg][c]      = r0v[i2];
            Bl[i2 * 64 + rg + 32][c] = r1v[i2];
        }
        __syncthreads();
    }
    // backward: B[i] -= N[q][i]^T * B[q]
    for (int q = 8; q >= 1; --q) {
        for (int i2 = 0; i2 < q; ++i2) {
            const double* Nblk = Nb + ((size_t)q * 9 + i2) * 4096;
            double a0 = 0.0, a1 = 0.0;
            for (int k = 0; k < 64; ++k) {
                double bk = Bl[q * 64 + k][c];
                a0 += Nblk[k * 64 + rg] * bk;
                a1 += Nblk[k * 64 + rg + 32] * bk;
            }
            Bl[i2 * 64 + rg][c]      -= a0;
            Bl[i2 * 64 + rg + 32][c] -= a1;
        }
        __syncthreads();
    }
    // xfinal: X[i] = Dinv_i^T * B[i]
    {
        double r0v[9], r1v[9];
#pragma unroll
        for (int i2 = 0; i2 < 9; ++i2) {
            const double* Dv = Dinv + (size_t)i2 * 4096;
            double a0 = 0.0, a1 = 0.0;
            for (int k = 0; k < 64; ++k) {
                double bk = Bl[i2 * 64 + k][c];
                a0 += Dv[k * 64 + rg] * bk;
                a1 += Dv[k * 64 + rg + 32] * bk;
            }
            r0v[i2] = a0; r1v[i2] = a1;
        }
#pragma unroll
        for (int i2 = 0; i2 < 9; ++i2) {
            int gi0 = i2 * 64 + rg, gi1 = i2 * 64 + rg + 32;
            if (gi0 < NAUG) Xs[gi0 * 32 + c] = (float)r0v[i2];
            if (gi1 < NAUG) Xs[gi1 * 32 + c] = (float)r1v[i2];
        }
    }
}

// ---------------------------------------------------------------------------
// Kernel 13: out = Phi @ X   (8192 x 513 x 32), X staged in LDS
// ---------------------------------------------------------------------------
__global__ __launch_bounds__(256) void out_gemm(const float* __restrict__ Phi,
                                                const float* __restrict__ Xs,
                                                float* __restrict__ outp)
{
    __shared__ float sX[NAUG * 32];
    const int tid = threadIdx.x;
    for (int i2 = tid; i2 < NAUG * 32; i2 += 256) sX[i2] = Xs[i2];
    __syncthreads();
    int rt = tid >> 5, c = tid & 31;
    int i0 = blockIdx.x * 32;
    for (int i = i0 + rt; i < i0 + 32; i += 8) {
        const float* prow = &Phi[(size_t)i * LDP];
        float acc = 0.0f;
        for (int k = 0; k < 512; k += 4) {
            float4 p = *(const float4*)&prow[k];
            acc = fmaf(p.x, sX[(k + 0) * 32 + c], acc);
            acc = fmaf(p.y, sX[(k + 1) * 32 + c], acc);
            acc = fmaf(p.z, sX[(k + 2) * 32 + c], acc);
            acc = fmaf(p.w, sX[(k + 3) * 32 + c], acc);
        }
        acc = fmaf(prow[512], sX[512 * 32 + c], acc);
        outp[(size_t)i * 32 + c] = acc;
    }
}

// ---------------------------------------------------------------------------
extern "C" void kernel_launch(void* const* d_in, const int* in_sizes, int n_in,
                              void* d_out, int out_size, void* d_ws, size_t ws_size,
                              hipStream_t stream)
{
    const float* x  = (const float*)d_in[0];   // (8192, 2048)
    const float* y  = (const float*)d_in[1];   // (8192, 32)
    const float* W1 = (const float*)d_in[2];   // (512, 2048)
    const float* b1 = (const float*)d_in[3];   // (512,)
    const float* W0 = (const float*)d_in[4];   // (513, 32)

    char* base = (char*)d_ws;
    float*  Phi  = (float*)base;                          // 18,874,368 B
    double* Gd   = (double*)(base + 20201472);            //  2,654,208 B
    double* By   = (double*)(base + 22855680);            //    147,456 B
    double* Dinv = (double*)(base + 23003136);            //    294,912 B
    float*  Xs   = (float*)(base + 23298048);             //     69,632 B
    double* Mb   = (double*)(base + 23367680);            //  2,654,208 B
    double* Nb   = (double*)(base + 26021888);            //  2,654,208 B
    unsigned short* xhi = (unsigned short*)(base + 28676096);   // 33,554,432 B
    unsigned short* xlo = (unsigned short*)(base + 62230528);   // 33,554,432 B
    unsigned short* whi = (unsigned short*)(base + 95784960);   //  2,097,152 B
    unsigned short* wlo = (unsigned short*)(base + 97882112);   //  2,097,152 B
    // aliases into xhi region (dead after phi_mfma):
    double* Gp   = (double*)(base + 28676096);            // 11,141,120 B
    double* Lmat = (double*)(base + 39817216);            //  2,654,208 B
    float* outp = (float*)d_out;

    split32<<<2048, 256, 0, stream>>>(x,  xhi, xlo, NROWS * DIN / 4);
    split32<<<1024, 256, 0, stream>>>(W1, whi, wlo, HF * DIN / 4);
    phi_mfma<<<512, 256, 0, stream>>>(xhi, xlo, whi, wlo, b1, Phi);
    aux_fill<<<32, 256, 0, stream>>>(Phi);
    gd_init<<<(NPAD * NPAD) / 256, 256, 0, stream>>>(Gd);
    gram_part<<<170 * 8, 256, 0, stream>>>(Phi, y, Gp);
    gram_reduce<<<170, 256, 0, stream>>>(Gp, Gd, By);
    for (int p = 0; p < 9; ++p) {
        chol_diag<<<1, 256, 0, stream>>>(Gd, Dinv, p);
        int m = 8 - p;
        if (m > 0)
            panel_up<<<m * (m + 1) / 2, 256, 0, stream>>>(Gd, Dinv, Lmat, p);
    }
    mnprep<<<72, 256, 0, stream>>>(Lmat, Dinv, Mb, Nb);
    sweep_all<<<1, 1024, 0, stream>>>(Mb, Nb, Dinv, By, W0, Xs);
    out_gemm<<<NROWS / 32, 256, 0, stream>>>(Phi, Xs, outp);
}